// Round 11
// baseline (1144.886 us; speedup 1.0000x reference)
//
#include <hip/hip_runtime.h>

// ---------------------------------------------------------------------------
// GraphSAGE GNN forward, MI355X round 25:
//  - attn: K-from-global kept (r24), but O now written into the Q region
//    (qoff) instead of K region. r24's failure: O->koff overwrote K that
//    other waves still read (Ks LDS snapshot used to hide this). Q rows are
//    wave-local (read into regs at qt start, written at qt end) -> race-free.
//    Out-proj GEMM input switched qkvb+C_ -> qkvb accordingly.
//  - LDS 75KB => 2 blocks/CU (occupancy 20%->~40%).
// ---------------------------------------------------------------------------

#define N_TOT   65536
#define B_GR    128
#define NP_     512
#define E_TOT   524288
#define EPG     4096
#define DIN_    128
#define C_      256
#define C3_     768
#define H_      4

typedef unsigned int uint;
typedef unsigned short ushort;

// param pool element offsets (ushorts)
#define O_L0LW  0u
#define O_L0LB  32768u
#define O_L0RW  33024u
#define O_L0RES 65792u
#define O_LWL   98560u
#define O_LBL   295168u
#define O_LWR   295936u
#define O_GNW   492544u
#define O_GNB   493568u
#define O_GNA   494592u
#define O_AIW   495616u
#define O_AIB   692224u
#define O_AOW   692992u
#define O_AOB   758528u
#define O_LNW   758784u
#define O_LNB   759040u
#define O_PLW   759296u
#define O_PLB   955904u
#define TOTALP  956160u

typedef __attribute__((ext_vector_type(8))) short bf16x8_t;
typedef __attribute__((ext_vector_type(4))) float f32x4_t;

__device__ __forceinline__ float bf2f(ushort u){ union{uint i; float f;} v; v.i = ((uint)u) << 16; return v.f; }
__device__ __forceinline__ ushort f2bf(float f){
  union{float f; uint u;} v; v.f = f;
  uint u = v.u;
  u += 0x7fffu + ((u >> 16) & 1u);   // RNE
  return (ushort)(u >> 16);
}
__device__ __forceinline__ uint pack2(float a, float b){ return (uint)f2bf(a) | ((uint)f2bf(b) << 16); }
__device__ __forceinline__ float u2f_lo(uint u){ union{uint i; float f;} v; v.i = u << 16; return v.f; }
__device__ __forceinline__ float u2f_hi(uint u){ union{uint i; float f;} v; v.i = u & 0xffff0000u; return v.f; }
__device__ __forceinline__ float gelu_f(float x){ return 0.5f * x * (1.0f + erff(x * 0.70710678118654752440f)); }
__device__ __forceinline__ float wredsum(float v){
  #pragma unroll
  for (int off = 32; off; off >>= 1) v += __shfl_xor(v, off, 64);
  return v;
}

// ---------------------------------------------------------------------------
// dtype probe: gn_w[0]==1.0. f32 -> 0x3F800000 ; bf16 pair -> 0x3F803F80
__global__ void probe_dtype(const uint* __restrict__ gnw_raw, uint* __restrict__ flag){
  if (threadIdx.x == 0 && blockIdx.x == 0)
    *flag = (gnw_raw[0] == 0x3F800000u) ? 1u : 0u;   // 1 = f32 inputs
}

struct Seg { const void* p; uint ofs; };
struct CvtArgs { Seg s[19]; };

__global__ __launch_bounds__(256) void cvt_params(CvtArgs a, ushort* __restrict__ pb,
                                                  const uint* __restrict__ flag){
  uint gi = blockIdx.x * 256u + threadIdx.x;
  if (gi >= TOTALP) return;
  int lo = 0;
  #pragma unroll
  for (int s = 1; s < 18; ++s) if (gi >= a.s[s].ofs) lo = s;
  uint rel = gi - a.s[lo].ofs;
  pb[gi] = (*flag) ? f2bf(((const float*)a.s[lo].p)[rel]) : ((const ushort*)a.s[lo].p)[rel];
}

// 4 elements per thread
__global__ __launch_bounds__(256) void cvt_flat(const void* __restrict__ in, ushort* __restrict__ out,
                                                const uint* __restrict__ flag){
  uint i4 = (blockIdx.x * 256u + threadIdx.x) * 4u;
  if (*flag) {
    float4 f = *(const float4*)((const float*)in + i4);
    uint2 o; o.x = pack2(f.x, f.y); o.y = pack2(f.z, f.w);
    *(uint2*)(out + i4) = o;
  } else {
    *(uint2*)(out + i4) = *(const uint2*)((const ushort*)in + i4);
  }
}

// ---------------------------------------------------------------------------
__global__ void deg_count(const int* __restrict__ dst, uint* __restrict__ deg){
  int e = blockIdx.x * 256 + threadIdx.x;
  atomicAdd(&deg[dst[e]], 1u);
}

__global__ __launch_bounds__(512) void scan_deg(const uint* __restrict__ deg,
    uint* __restrict__ rowptr, uint* __restrict__ cursor)
{
  __shared__ uint s[512];
  const int g = blockIdx.x, tid = threadIdx.x;
  uint v = deg[g * NP_ + tid];
  s[tid] = v;
  __syncthreads();
  #pragma unroll
  for (int off = 1; off < 512; off <<= 1) {
    uint t = (tid >= off) ? s[tid - off] : 0u;
    __syncthreads();
    s[tid] += t;
    __syncthreads();
  }
  uint p = g * EPG + (s[tid] - v);
  rowptr[g * NP_ + tid] = p;
  cursor[g * NP_ + tid] = p;
}

__global__ void scatter_edges(const int* __restrict__ src, const int* __restrict__ dst,
    uint* __restrict__ cursor, int* __restrict__ csr)
{
  int e = blockIdx.x * 256 + threadIdx.x;
  uint p = atomicAdd(&cursor[dst[e]], 1u);
  csr[p] = src[e];
}

// ---------------------------------------------------------------------------
// CSR mean-aggregation: one wave per node. Lane owns D/64 channels.
template<int D>
__global__ __launch_bounds__(256) void sage_agg_csr(const ushort* __restrict__ X,
    const int* __restrict__ csr, const uint* __restrict__ rowptr,
    const uint* __restrict__ deg, ushort* __restrict__ agg)
{
  constexpr int CPL = D / 64;
  const int tid = threadIdx.x, lane = tid & 63, wave = tid >> 6;
  const int n = blockIdx.x * 4 + wave;
  const uint start = rowptr[n];
  const uint dg = deg[n];
  const int co = lane * CPL;
  float acc[CPL];
  #pragma unroll
  for (int k = 0; k < CPL; ++k) acc[k] = 0.0f;

  auto addrow = [&](int s) {
    const ushort* r = X + (size_t)s * D + co;
    if constexpr (CPL == 2) {
      uint u = *(const uint*)r;
      acc[0] += u2f_lo(u); acc[1] += u2f_hi(u);
    } else {
      uint2 u = *(const uint2*)r;
      acc[0] += u2f_lo(u.x); acc[1] += u2f_hi(u.x);
      acc[2] += u2f_lo(u.y); acc[3] += u2f_hi(u.y);
    }
  };

  uint j = 0;
  for (; j + 4 <= dg; j += 4) {
    int s0 = csr[start + j],     s1 = csr[start + j + 1];
    int s2 = csr[start + j + 2], s3 = csr[start + j + 3];
    addrow(s0); addrow(s1); addrow(s2); addrow(s3);
  }
  for (; j < dg; ++j) addrow(csr[start + j]);

  float inv = 1.0f / (float)(dg < 1u ? 1u : dg);
  ushort* op = agg + (size_t)n * D + co;
  if constexpr (CPL == 2) {
    *(uint*)op = pack2(acc[0] * inv, acc[1] * inv);
  } else {
    uint2 o; o.x = pack2(acc[0] * inv, acc[1] * inv);
    o.y = pack2(acc[2] * inv, acc[3] * inv);
    *(uint2*)op = o;
  }
}

// ---------------------------------------------------------------------------
// MFMA GEMM v6: 64x256 block, 4 waves, wave = 64x64. A via LDS, W direct.
// K is COMPILE-TIME (128/256): K-loop unrolls, loads schedule across iters.
// Epilogue: block-wide 32x260 staging -> full 512B-row stores.
// RN: fused row-L2-normalize + GraphNorm moments. LN: fused graph-LN stats.
#define CS_P 260
template<int K, bool DUAL, bool RN, bool LN>
__global__ __launch_bounds__(256, 4) void gemm_mfma(
    const ushort* __restrict__ A1, int lda1, const ushort* __restrict__ W1,
    const ushort* __restrict__ A2, int lda2, const ushort* __restrict__ W2,
    const ushort* __restrict__ bias, const ushort* addend,   // addend may alias out
    ushort* out, int ldOut,
    float* __restrict__ m1, float* __restrict__ m2, float* __restrict__ st2)
{
  __shared__ __align__(16) unsigned char smem[34816];   // max(64*(K+8)*2, 32*260*4)
  ushort* As = (ushort*)smem;
  float*  Cs = (float*)smem;
  const int tid = threadIdx.x;
  const int lane = tid & 63, wave = tid >> 6;
  const int lr = lane & 15, quad = lane >> 4;
  const int m0 = blockIdx.x * 64;
  const int n0b = blockIdx.y * 256;
  const int n0 = n0b + wave * 64;
  constexpr int KP = K + 8;
  f32x4_t acc[4][4];
  #pragma unroll
  for (int rt = 0; rt < 4; ++rt)
    #pragma unroll
    for (int ct = 0; ct < 4; ++ct) acc[rt][ct] = (f32x4_t){0.f, 0.f, 0.f, 0.f};

  constexpr int lpr = K >> 3;
  constexpr int rpp = 256 / lpr;
  constexpr int passes = 64 / rpp;
  const int tr = tid / lpr, tc = (tid % lpr) * 8;

  // ---- stream 1 ----
  #pragma unroll
  for (int p = 0; p < passes; ++p) {
    int row = p * rpp + tr;
    *(bf16x8_t*)(As + row * KP + tc) =
        *(const bf16x8_t*)(A1 + (size_t)(m0 + row) * lda1 + tc);
  }
  __syncthreads();
  {
    const ushort* wp = W1 + (size_t)(n0 + lr) * K + quad * 8;
    for (int kb = 0; kb < K; kb += 32) {
      bf16x8_t a[4], b[4];
      #pragma unroll
      for (int ct = 0; ct < 4; ++ct) b[ct] = *(const bf16x8_t*)(wp + (size_t)(ct * 16) * K + kb);
      #pragma unroll
      for (int rt = 0; rt < 4; ++rt)
        a[rt] = *(const bf16x8_t*)(As + (rt * 16 + lr) * KP + kb + quad * 8);
      #pragma unroll
      for (int rt = 0; rt < 4; ++rt)
        #pragma unroll
        for (int ct = 0; ct < 4; ++ct)
          acc[rt][ct] = __builtin_amdgcn_mfma_f32_16x16x32_bf16(a[rt], b[ct], acc[rt][ct], 0, 0, 0);
    }
  }
  __syncthreads();
  // ---- stream 2 ----
  if constexpr (DUAL) {
    #pragma unroll
    for (int p = 0; p < passes; ++p) {
      int row = p * rpp + tr;
      *(bf16x8_t*)(As + row * KP + tc) =
          *(const bf16x8_t*)(A2 + (size_t)(m0 + row) * lda2 + tc);
    }
    __syncthreads();
    const ushort* wp = W2 + (size_t)(n0 + lr) * K + quad * 8;
    for (int kb = 0; kb < K; kb += 32) {
      bf16x8_t a[4], b[4];
      #pragma unroll
      for (int ct = 0; ct < 4; ++ct) b[ct] = *(const bf16x8_t*)(wp + (size_t)(ct * 16) * K + kb);
      #pragma unroll
      for (int rt = 0; rt < 4; ++rt)
        a[rt] = *(const bf16x8_t*)(As + (rt * 16 + lr) * KP + kb + quad * 8);
      #pragma unroll
      for (int rt = 0; rt < 4; ++rt)
        #pragma unroll
        for (int ct = 0; ct < 4; ++ct)
          acc[rt][ct] = __builtin_amdgcn_mfma_f32_16x16x32_bf16(a[rt], b[ct], acc[rt][ct], 0, 0, 0);
    }
    __syncthreads();
  }

  // ---- epilogue ----
  float bvs[4];
  if (RN && bias) {
    #pragma unroll
    for (int ct = 0; ct < 4; ++ct) bvs[ct] = bf2f(bias[n0 + ct * 16 + lr]);
  }
  float bvL[4] = {0.f, 0.f, 0.f, 0.f};
  if (!RN && bias) {
    #pragma unroll
    for (int j = 0; j < 4; ++j) bvL[j] = bf2f(bias[n0b + lane * 4 + j]);
  }
  float a1s[4] = {0.f, 0.f, 0.f, 0.f}, a2s[4] = {0.f, 0.f, 0.f, 0.f};
  float sln = 0.0f, qln = 0.0f;
  #pragma unroll
  for (int round = 0; round < 2; ++round) {
    #pragma unroll
    for (int rt2 = 0; rt2 < 2; ++rt2) {
      int rt = round * 2 + rt2;
      #pragma unroll
      for (int ct = 0; ct < 4; ++ct)
        #pragma unroll
        for (int r = 0; r < 4; ++r) {
          float v = acc[rt][ct][r];
          if constexpr (RN) v += bias ? bvs[ct] : 0.0f;
          Cs[(rt2 * 16 + quad * 4 + r) * CS_P + wave * 64 + ct * 16 + lr] = v;
        }
    }
    __syncthreads();
    #pragma unroll
    for (int it = 0; it < 8; ++it) {
      int row = wave * 8 + it;
      float4 v = *(const float4*)(Cs + row * CS_P + lane * 4);
      int grow = m0 + round * 32 + row;
      size_t ob = (size_t)grow * ldOut + n0b + lane * 4;
      if constexpr (RN) {
        float ss = v.x*v.x + v.y*v.y + v.z*v.z + v.w*v.w;
        ss = wredsum(ss);
        float inv = 1.0f / fmaxf(sqrtf(ss), 1e-12f);
        float r0 = v.x * inv, r1 = v.y * inv, r2 = v.z * inv, r3 = v.w * inv;
        a1s[0] += r0; a1s[1] += r1; a1s[2] += r2; a1s[3] += r3;
        a2s[0] += r0*r0; a2s[1] += r1*r1; a2s[2] += r2*r2; a2s[3] += r3*r3;
        uint2 o; o.x = pack2(r0, r1); o.y = pack2(r2, r3);
        *(uint2*)(out + ob) = o;
      } else {
        float r0 = v.x + bvL[0], r1 = v.y + bvL[1], r2 = v.z + bvL[2], r3 = v.w + bvL[3];
        if (addend) {
          uint2 ad = *(const uint2*)(addend + ob);
          r0 += u2f_lo(ad.x); r1 += u2f_hi(ad.x);
          r2 += u2f_lo(ad.y); r3 += u2f_hi(ad.y);
        }
        if constexpr (LN) {
          sln += r0 + r1 + r2 + r3;
          qln += r0*r0 + r1*r1 + r2*r2 + r3*r3;
        }
        uint2 o; o.x = pack2(r0, r1); o.y = pack2(r2, r3);
        *(uint2*)(out + ob) = o;
      }
    }
    __syncthreads();
  }
  if constexpr (RN) {
    const int g = m0 >> 9;
    #pragma unroll
    for (int k = 0; k < 4; ++k) {
      atomicAdd(&m1[g*C_ + lane * 4 + k], a1s[k]);
      atomicAdd(&m2[g*C_ + lane * 4 + k], a2s[k]);
    }
  }
  if constexpr (LN) {
    const int g = m0 >> 9;
    sln = wredsum(sln); qln = wredsum(qln);
    if (lane == 0) {
      atomicAdd(&st2[g * 2], sln);
      atomicAdd(&st2[g * 2 + 1], qln);
    }
  }
}

// ---------------------------------------------------------------------------
// GraphNorm + GELU + residual, param-cached. Block = 64 nodes of one graph;
// thread owns a fixed 8-channel slice. Params loaded ONCE, folded.
__global__ __launch_bounds__(256) void gn_gelu_add(const ushort* __restrict__ h,
    const ushort* res,
    const float* __restrict__ m1, const float* __restrict__ m2,
    const ushort* __restrict__ gw, const ushort* __restrict__ gb, const ushort* __restrict__ ga,
    ushort* out)
{
  const int tid = threadIdx.x;
  const int c = (tid * 8) & (C_ - 1);
  const int rowoff = tid >> 5;            // 0..7
  const int n0 = blockIdx.x * 64;
  const int g = n0 >> 9;
  float am[8], rs[8], bb[8];
  #pragma unroll
  for (int j = 0; j < 8; ++j) {
    int cc = c + j;
    float a  = bf2f(ga[cc]);
    float mm = m1[g*C_ + cc] * (1.0f / 512.0f);
    float q2 = m2[g*C_ + cc] * (1.0f / 512.0f);
    float var = q2 - a * (2.0f - a) * mm * mm;
    am[j] = a * mm;
    rs[j] = bf2f(gw[cc]) * rsqrtf(var + 1e-5f);
    bb[j] = bf2f(gb[cc]);
  }
  const size_t b0 = (size_t)(n0 + rowoff) * C_ + c;
  const ushort* hp = h + b0;
  const ushort* rp = res + b0;
  ushort* op = out + b0;
  #pragma unroll
  for (int p = 0; p < 8; ++p) {
    const size_t off = (size_t)p * 8 * C_;
    uint4 hv = *(const uint4*)(hp + off);
    uint4 rv = *(const uint4*)(rp + off);
    float hh[8] = {u2f_lo(hv.x), u2f_hi(hv.x), u2f_lo(hv.y), u2f_hi(hv.y),
                   u2f_lo(hv.z), u2f_hi(hv.z), u2f_lo(hv.w), u2f_hi(hv.w)};
    float rr[8] = {u2f_lo(rv.x), u2f_hi(rv.x), u2f_lo(rv.y), u2f_hi(rv.y),
                   u2f_lo(rv.z), u2f_hi(rv.z), u2f_lo(rv.w), u2f_hi(rv.w)};
    float oo[8];
    #pragma unroll
    for (int j = 0; j < 8; ++j) {
      float y = (hh[j] - am[j]) * rs[j] + bb[j];
      oo[j] = gelu_f(y) + rr[j];
    }
    uint4 ov;
    ov.x = pack2(oo[0], oo[1]); ov.y = pack2(oo[2], oo[3]);
    ov.z = pack2(oo[4], oo[5]); ov.w = pack2(oo[6], oo[7]);
    *(uint4*)(op + off) = ov;
  }
}

// ---------------------------------------------------------------------------
// MFMA attention: one block (512 thr) per (graph, head). Vt XOR-swizzled.
// K read directly from global (L2-resident); O written into Q region (wave-
// local rows, consumed-before-written). LDS 75KB => 2 blocks/CU.
#define VT_P 520
#define PW_P 40
__device__ __forceinline__ int vswz(int c){ return ((c >> 3) & 7) << 3; }
__global__ __launch_bounds__(512, 2) void attn_kernel(ushort* __restrict__ qkv)
{
  __shared__ __align__(16) ushort Vt[64 * VT_P];
  __shared__ ushort Pw[8][16 * PW_P];
  const int bid = blockIdx.x;
  const int g = bid >> 2, h = bid & 3;
  const int tid = threadIdx.x, lane = tid & 63, wave = tid >> 6;
  const int lr = lane & 15, quad = lane >> 4;
  const size_t base = (size_t)g * NP_ * C3_;
  const int qoff = h * 64, koff = C_ + h * 64, voff = 2 * C_ + h * 64;
  // staging: V only (b128 global loads, XOR-swizzled transpose layout)
  for (int idx = tid; idx < NP_ * 8; idx += 512) {
    int j = idx >> 3, c8 = (idx & 7) << 3;
    bf16x8_t vv = *(const bf16x8_t*)(qkv + base + (size_t)j * C3_ + voff + c8);
    #pragma unroll
    for (int m = 0; m < 8; ++m) {
      int c = c8 + m;
      Vt[c * VT_P + (j ^ vswz(c))] = (ushort)vv[m];
    }
  }
  __syncthreads();
  ushort* pw = &Pw[wave][0];
  const ushort* kb = qkv + base + koff;
  const int q0 = wave * 64;
  for (int qt = 0; qt < 4; ++qt) {
    const int qr = q0 + qt * 16;
    const ushort* qp = qkv + base + (size_t)(qr + lr) * C3_ + qoff + quad * 8;
    bf16x8_t qa0 = *(const bf16x8_t*)(qp);
    bf16x8_t qa1 = *(const bf16x8_t*)(qp + 32);
    f32x4_t s[32];
    #pragma unroll
    for (int t = 0; t < 32; ++t) {
      const ushort* kp = kb + (size_t)(t * 16 + lr) * C3_ + quad * 8;
      bf16x8_t b0 = *(const bf16x8_t*)(kp);
      bf16x8_t b1 = *(const bf16x8_t*)(kp + 32);
      f32x4_t a = (f32x4_t){0.f, 0.f, 0.f, 0.f};
      a = __builtin_amdgcn_mfma_f32_16x16x32_bf16(qa0, b0, a, 0, 0, 0);
      a = __builtin_amdgcn_mfma_f32_16x16x32_bf16(qa1, b1, a, 0, 0, 0);
      s[t] = a;
    }
    float invv[4];
    #pragma unroll
    for (int r = 0; r < 4; ++r) {
      float m = s[0][r];
      #pragma unroll
      for (int t = 1; t < 32; ++t) m = fmaxf(m, s[t][r]);
      #pragma unroll
      for (int off = 8; off; off >>= 1) m = fmaxf(m, __shfl_xor(m, off, 64));
      float sm = 0.0f;
      #pragma unroll
      for (int t = 0; t < 32; ++t) {
        float e = __expf((s[t][r] - m) * 0.125f);
        s[t][r] = e; sm += e;
      }
      #pragma unroll
      for (int off = 8; off; off >>= 1) sm += __shfl_xor(sm, off, 64);
      invv[r] = 1.0f / sm;
    }
    f32x4_t o[4];
    #pragma unroll
    for (int t = 0; t < 4; ++t) o[t] = (f32x4_t){0.f, 0.f, 0.f, 0.f};
    for (int kc = 0; kc < 16; ++kc) {
      #pragma unroll
      for (int half = 0; half < 2; ++half) {
        int t = kc * 2 + half;
        #pragma unroll
        for (int r = 0; r < 4; ++r)
          pw[(quad * 4 + r) * PW_P + half * 16 + lr] = f2bf(s[t][r] * invv[r]);
      }
      __threadfence_block();
      bf16x8_t pa = *(const bf16x8_t*)(pw + lr * PW_P + quad * 8);
      #pragma unroll
      for (int nt = 0; nt < 4; ++nt) {
        int vrow = nt * 16 + lr;
        const ushort* vp = Vt + (size_t)vrow * VT_P + ((kc * 32 + quad * 8) ^ vswz(vrow));
        bf16x8_t b = *(const bf16x8_t*)(vp);
        o[nt] = __builtin_amdgcn_mfma_f32_16x16x32_bf16(pa, b, o[nt], 0, 0, 0);
      }
    }
    // O -> Q region (rows qr..qr+15 of this wave, already consumed)
    #pragma unroll
    for (int nt = 0; nt < 4; ++nt)
      #pragma unroll
      for (int r = 0; r < 4; ++r)
        qkv[base + (size_t)(qr + quad * 4 + r) * C3_ + qoff + nt * 16 + lr] =
            f2bf(o[nt][r]);
  }
}

// ---------------------------------------------------------------------------
// ln_gelu, param-cached: block = 64 nodes of one graph, thread = fixed 8 ch.
__global__ __launch_bounds__(256) void ln_gelu(const ushort* __restrict__ x2, const float* __restrict__ st2,
    const ushort* __restrict__ lw, const ushort* __restrict__ lb, ushort* __restrict__ x3)
{
  const int tid = threadIdx.x;
  const int c = (tid * 8) & (C_ - 1);
  const int rowoff = tid >> 5;
  const int n0 = blockIdx.x * 64;
  const int g = n0 >> 9;
  float S = st2[g * 2], Q = st2[g * 2 + 1];
  float mu = S * (1.0f / (NP_ * C_));
  float var = Q * (1.0f / (NP_ * C_)) - mu * mu;
  float rsg = rsqrtf(var + 1e-5f);
  float ww[8], bb[8];
  #pragma unroll
  for (int j = 0; j < 8; ++j) {
    int cc = c + j;
    ww[j] = rsg * bf2f(lw[cc]);
    bb[j] = bf2f(lb[cc]);
  }
  const size_t b0 = (size_t)(n0 + rowoff) * C_ + c;
  const ushort* xp = x2 + b0;
  ushort* op = x3 + b0;
  #pragma unroll
  for (int p = 0; p < 8; ++p) {
    const size_t off = (size_t)p * 8 * C_;
    uint4 v = *(const uint4*)(xp + off);
    float vv[8] = {u2f_lo(v.x), u2f_hi(v.x), u2f_lo(v.y), u2f_hi(v.y),
                   u2f_lo(v.z), u2f_hi(v.z), u2f_lo(v.w), u2f_hi(v.w)};
    float oo[8];
    #pragma unroll
    for (int j = 0; j < 8; ++j) {
      float y = (vv[j] - mu) * ww[j] + bb[j];
      oo[j] = gelu_f(y);
    }
    uint4 ov;
    ov.x = pack2(oo[0], oo[1]); ov.y = pack2(oo[2], oo[3]);
    ov.z = pack2(oo[4], oo[5]); ov.w = pack2(oo[6], oo[7]);
    *(uint4*)(op + off) = ov;
  }
}

// ---------------------------------------------------------------------------
// Pool: per-slice partials (grid 128x8) then fused combine+projection.
__global__ __launch_bounds__(256) void pool_part(const ushort* __restrict__ x3,
    float* __restrict__ psum, float* __restrict__ pmax)
{
  const int g = blockIdx.x, sl = blockIdx.y, c = threadIdx.x;
  const ushort* p = x3 + ((size_t)g * NP_ + sl * 64) * C_ + c;
  float s = 0.0f, mx = -3.0e38f;
  #pragma unroll 4
  for (int r = 0; r < 64; ++r) {
    float v = bf2f(p[(size_t)r * C_]);
    s += v; mx = fmaxf(mx, v);
  }
  psum[((size_t)g * 8 + sl) * C_ + c] = s;
  pmax[((size_t)g * 8 + sl) * C_ + c] = mx;
}

__global__ __launch_bounds__(256) void final_gemm(const float* __restrict__ psum,
    const float* __restrict__ pmax,
    const ushort* __restrict__ W, const ushort* __restrict__ b, void* __restrict__ out,
    const uint* __restrict__ flag)
{
  __shared__ float pl[C3_];
  const int g = blockIdx.x, c = threadIdx.x;
  float s = 0.0f, mx = -3.0e38f;
  #pragma unroll
  for (int sl = 0; sl < 8; ++sl) {
    s += psum[((size_t)g * 8 + sl) * C_ + c];
    mx = fmaxf(mx, pmax[((size_t)g * 8 + sl) * C_ + c]);
  }
  pl[c] = s * (1.0f / 512.0f);
  pl[C_ + c] = mx;
  pl[2 * C_ + c] = s;
  __syncthreads();
  float acc = bf2f(b[c]);
  const ushort* wr = W + (size_t)c * C3_;
  for (int k = 0; k < C3_; k += 2) {
    uint wv = *(const uint*)(wr + k);
    acc += pl[k] * u2f_lo(wv) + pl[k + 1] * u2f_hi(wv);
  }
  if (*flag) ((float*)out)[g * C_ + c] = acc;
  else       ((ushort*)out)[g * C_ + c] = f2bf(acc);
}

// ---------------------------------------------------------------------------
extern "C" void kernel_launch(void* const* d_in, const int* in_sizes, int n_in,
                              void* d_out, int out_size, void* d_ws, size_t ws_size,
                              hipStream_t stream)
{
  const int* ei   = (const int*)d_in[1];
  const int* srcp = ei;
  const int* dstp = ei + E_TOT;

  const size_t NC = (size_t)N_TOT * C_;                        // 16,777,216
  const size_t NEEDED = (4ull << 20) + 4 * NC * sizeof(ushort); // 132 MB
  if (ws_size < NEEDED) return;

  unsigned char* wsb = (unsigned char*)d_ws;
  uint*   deg    = (uint*)wsb;                          // 256 KB
  float*  mbuf   = (float*)(wsb + (256u << 10));        // 4 layers x (m1,m2) = 1 MB
  float*  st2    = (float*)(wsb + (1280u << 10));       // ln sums 1 KB (zeroed w/ mbuf)
  uint*   flag   = (uint*)(wsb + (1288u << 10));
  ushort* PB     = (ushort*)(wsb + (1792u << 10));      // param pool bf16 ~1.9MB
  ushort* S0     = (ushort*)(wsb + (4u << 20));         // x1
  ushort* S1     = S0 + NC;
  ushort* S2     = S1 + NC;
  ushort* S3     = S2 + NC;
  ushort* qkvb   = S1;                                  // [N][768] overlay
  ushort* XB     = S3;                                  // x bf16 (lower 16MB of S3)
  unsigned char* s3hi = (unsigned char*)(S3 + (size_t)N_TOT * DIN_);
  int*  csr    = (int*)s3hi;                            // 2 MB
  uint* rowptr = (uint*)(s3hi + (2u << 20));            // 256 KB
  uint* cursor = (uint*)(s3hi + (2u << 20) + (256u << 10));
  float* psum  = (float*)S2;                            // pool partials (S2 dead then)
  float* pmax  = psum + (size_t)B_GR * 8 * C_;

  // ---- dtype probe + import ----
  probe_dtype<<<1, 1, 0, stream>>>((const uint*)d_in[10], flag);
  CvtArgs ca;
  ca.s[0]  = { d_in[3],  O_L0LW };  ca.s[1]  = { d_in[4],  O_L0LB };
  ca.s[2]  = { d_in[5],  O_L0RW };  ca.s[3]  = { d_in[6],  O_L0RES };
  ca.s[4]  = { d_in[7],  O_LWL  };  ca.s[5]  = { d_in[8],  O_LBL  };
  ca.s[6]  = { d_in[9],  O_LWR  };  ca.s[7]  = { d_in[10], O_GNW  };
  ca.s[8]  = { d_in[11], O_GNB  };  ca.s[9]  = { d_in[12], O_GNA  };
  ca.s[10] = { d_in[13], O_AIW  };  ca.s[11] = { d_in[14], O_AIB  };
  ca.s[12] = { d_in[15], O_AOW  };  ca.s[13] = { d_in[16], O_AOB  };
  ca.s[14] = { d_in[17], O_LNW  };  ca.s[15] = { d_in[18], O_LNB  };
  ca.s[16] = { d_in[19], O_PLW  };  ca.s[17] = { d_in[20], O_PLB  };
  ca.s[18] = { nullptr,  TOTALP };
  cvt_params<<<(TOTALP + 255) / 256, 256, 0, stream>>>(ca, PB, flag);
  cvt_flat<<<(N_TOT * DIN_) / 1024, 256, 0, stream>>>(d_in[0], XB, flag);

  // ---- zero deg + moment buffers + ln sums (contiguous region) ----
  hipMemsetAsync(deg, 0, N_TOT * sizeof(uint), stream);
  hipMemsetAsync(mbuf, 0, (1u << 20) + 1024, stream);

  // ---- degree + CSR build ----
  deg_count<<<E_TOT / 256, 256, 0, stream>>>(dstp, deg);
  scan_deg<<<B_GR, 512, 0, stream>>>(deg, rowptr, cursor);
  scatter_edges<<<E_TOT / 256, 256, 0, stream>>>(srcp, dstp, cursor, csr);

  const size_t MSZ = (size_t)B_GR * C_;
  // ---- layer 0 (DIN=128 -> C=256) ----
  {
    float* m1 = mbuf;
    float* m2 = mbuf + MSZ * 4;
    sage_agg_csr<DIN_><<<N_TOT / 4, 256, 0, stream>>>(XB, csr, rowptr, deg, S1);
    gemm_mfma<DIN_, true, true, false><<<dim3(N_TOT / 64, 1), 256, 0, stream>>>(
        S1, DIN_, PB + O_L0LW, XB, DIN_, PB + O_L0RW, PB + O_L0LB, nullptr, S2, C_, m1, m2, nullptr);
    gemm_mfma<DIN_, false, false, false><<<dim3(N_TOT / 64, 1), 256, 0, stream>>>(
        XB, DIN_, PB + O_L0RES, nullptr, 0, nullptr, nullptr, nullptr, S0, C_, nullptr, nullptr, nullptr);
    gn_gelu_add<<<N_TOT / 64, 256, 0, stream>>>(S2, S0, m1, m2,
        PB + O_GNW, PB + O_GNB, PB + O_GNA, S0);
  }

  // ---- layers 1..3 (C -> C) ----
  for (int i = 0; i < 3; ++i) {
    float* m1 = mbuf + MSZ * (i + 1);
    float* m2 = mbuf + MSZ * 4 + MSZ * (i + 1);
    sage_agg_csr<C_><<<N_TOT / 4, 256, 0, stream>>>(S0, csr, rowptr, deg, S1);
    gemm_mfma<C_, true, true, false><<<dim3(N_TOT / 64, 1), 256, 0, stream>>>(
        S1, C_, PB + O_LWL + (size_t)i * C_ * C_, S0, C_, PB + O_LWR + (size_t)i * C_ * C_,
        PB + O_LBL + i * C_, nullptr, S2, C_, m1, m2, nullptr);
    gn_gelu_add<<<N_TOT / 64, 256, 0, stream>>>(S2, S0, m1, m2,
        PB + O_GNW + (i + 1) * C_, PB + O_GNB + (i + 1) * C_, PB + O_GNA + (i + 1) * C_, S0);
  }

  // ---- attention ----
  gemm_mfma<C_, false, false, false><<<dim3(N_TOT / 64, 3), 256, 0, stream>>>(
      S0, C_, PB + O_AIW, nullptr, 0, nullptr, PB + O_AIB, nullptr, qkvb, C3_, nullptr, nullptr, nullptr);
  attn_kernel<<<B_GR * H_, 512, 0, stream>>>(qkvb);
  // out-proj (+x1 residual) with fused graph-LN stats; O lives in Q region now
  gemm_mfma<C_, false, false, true><<<dim3(N_TOT / 64, 1), 256, 0, stream>>>(
      qkvb, C3_, PB + O_AOW, nullptr, 0, nullptr, PB + O_AOB, S0, S0, C_, nullptr, nullptr, st2);

  // ---- graph LayerNorm + gelu ----
  ln_gelu<<<N_TOT / 64, 256, 0, stream>>>(S0, st2, PB + O_LNW, PB + O_LNB, S1);

  // ---- pool + projection ----
  pool_part<<<dim3(B_GR, 8), 256, 0, stream>>>(S1, psum, pmax);
  final_gemm<<<B_GR, 256, 0, stream>>>(psum, pmax, PB + O_PLW, PB + O_PLB, d_out, flag);
}

// Round 13
// 867.197 us; speedup vs baseline: 1.3202x; 1.3202x over previous
//
#include <hip/hip_runtime.h>

// ---------------------------------------------------------------------------
// GraphSAGE GNN forward, MI355X round 27 == round 23/26 (verified best,
// 871.7us). Round-26 bench failed on container infrastructure, not kernel —
// resubmitting identical source for a clean re-bench.
// r24/r25 attn-occupancy experiments remain reverted: r24 O->K write race;
// r25 K-from-global caused 328MB HBM fetch (per-XCD L2 at capacity -> thrash).
// Session deltas vs 1021us start: param-cached gn_gelu/ln_gelu (-240us),
// compile-time-K GEMMs (-10us), b128 attn staging, vectorized elementwise.
// ---------------------------------------------------------------------------

#define N_TOT   65536
#define B_GR    128
#define NP_     512
#define E_TOT   524288
#define EPG     4096
#define DIN_    128
#define C_      256
#define C3_     768
#define H_      4

typedef unsigned int uint;
typedef unsigned short ushort;

// param pool element offsets (ushorts)
#define O_L0LW  0u
#define O_L0LB  32768u
#define O_L0RW  33024u
#define O_L0RES 65792u
#define O_LWL   98560u
#define O_LBL   295168u
#define O_LWR   295936u
#define O_GNW   492544u
#define O_GNB   493568u
#define O_GNA   494592u
#define O_AIW   495616u
#define O_AIB   692224u
#define O_AOW   692992u
#define O_AOB   758528u
#define O_LNW   758784u
#define O_LNB   759040u
#define O_PLW   759296u
#define O_PLB   955904u
#define TOTALP  956160u

typedef __attribute__((ext_vector_type(8))) short bf16x8_t;
typedef __attribute__((ext_vector_type(4))) float f32x4_t;

__device__ __forceinline__ float bf2f(ushort u){ union{uint i; float f;} v; v.i = ((uint)u) << 16; return v.f; }
__device__ __forceinline__ ushort f2bf(float f){
  union{float f; uint u;} v; v.f = f;
  uint u = v.u;
  u += 0x7fffu + ((u >> 16) & 1u);   // RNE
  return (ushort)(u >> 16);
}
__device__ __forceinline__ uint pack2(float a, float b){ return (uint)f2bf(a) | ((uint)f2bf(b) << 16); }
__device__ __forceinline__ float u2f_lo(uint u){ union{uint i; float f;} v; v.i = u << 16; return v.f; }
__device__ __forceinline__ float u2f_hi(uint u){ union{uint i; float f;} v; v.i = u & 0xffff0000u; return v.f; }
__device__ __forceinline__ float gelu_f(float x){ return 0.5f * x * (1.0f + erff(x * 0.70710678118654752440f)); }
__device__ __forceinline__ float wredsum(float v){
  #pragma unroll
  for (int off = 32; off; off >>= 1) v += __shfl_xor(v, off, 64);
  return v;
}

// ---------------------------------------------------------------------------
// dtype probe: gn_w[0]==1.0. f32 -> 0x3F800000 ; bf16 pair -> 0x3F803F80
__global__ void probe_dtype(const uint* __restrict__ gnw_raw, uint* __restrict__ flag){
  if (threadIdx.x == 0 && blockIdx.x == 0)
    *flag = (gnw_raw[0] == 0x3F800000u) ? 1u : 0u;   // 1 = f32 inputs
}

struct Seg { const void* p; uint ofs; };
struct CvtArgs { Seg s[19]; };

__global__ __launch_bounds__(256) void cvt_params(CvtArgs a, ushort* __restrict__ pb,
                                                  const uint* __restrict__ flag){
  uint gi = blockIdx.x * 256u + threadIdx.x;
  if (gi >= TOTALP) return;
  int lo = 0;
  #pragma unroll
  for (int s = 1; s < 18; ++s) if (gi >= a.s[s].ofs) lo = s;
  uint rel = gi - a.s[lo].ofs;
  pb[gi] = (*flag) ? f2bf(((const float*)a.s[lo].p)[rel]) : ((const ushort*)a.s[lo].p)[rel];
}

// 4 elements per thread
__global__ __launch_bounds__(256) void cvt_flat(const void* __restrict__ in, ushort* __restrict__ out,
                                                const uint* __restrict__ flag){
  uint i4 = (blockIdx.x * 256u + threadIdx.x) * 4u;
  if (*flag) {
    float4 f = *(const float4*)((const float*)in + i4);
    uint2 o; o.x = pack2(f.x, f.y); o.y = pack2(f.z, f.w);
    *(uint2*)(out + i4) = o;
  } else {
    *(uint2*)(out + i4) = *(const uint2*)((const ushort*)in + i4);
  }
}

// ---------------------------------------------------------------------------
__global__ void deg_count(const int* __restrict__ dst, uint* __restrict__ deg){
  int e = blockIdx.x * 256 + threadIdx.x;
  atomicAdd(&deg[dst[e]], 1u);
}

__global__ __launch_bounds__(512) void scan_deg(const uint* __restrict__ deg,
    uint* __restrict__ rowptr, uint* __restrict__ cursor)
{
  __shared__ uint s[512];
  const int g = blockIdx.x, tid = threadIdx.x;
  uint v = deg[g * NP_ + tid];
  s[tid] = v;
  __syncthreads();
  #pragma unroll
  for (int off = 1; off < 512; off <<= 1) {
    uint t = (tid >= off) ? s[tid - off] : 0u;
    __syncthreads();
    s[tid] += t;
    __syncthreads();
  }
  uint p = g * EPG + (s[tid] - v);
  rowptr[g * NP_ + tid] = p;
  cursor[g * NP_ + tid] = p;
}

__global__ void scatter_edges(const int* __restrict__ src, const int* __restrict__ dst,
    uint* __restrict__ cursor, int* __restrict__ csr)
{
  int e = blockIdx.x * 256 + threadIdx.x;
  uint p = atomicAdd(&cursor[dst[e]], 1u);
  csr[p] = src[e];
}

// ---------------------------------------------------------------------------
// CSR mean-aggregation: one wave per node. Lane owns D/64 channels.
template<int D>
__global__ __launch_bounds__(256) void sage_agg_csr(const ushort* __restrict__ X,
    const int* __restrict__ csr, const uint* __restrict__ rowptr,
    const uint* __restrict__ deg, ushort* __restrict__ agg)
{
  constexpr int CPL = D / 64;
  const int tid = threadIdx.x, lane = tid & 63, wave = tid >> 6;
  const int n = blockIdx.x * 4 + wave;
  const uint start = rowptr[n];
  const uint dg = deg[n];
  const int co = lane * CPL;
  float acc[CPL];
  #pragma unroll
  for (int k = 0; k < CPL; ++k) acc[k] = 0.0f;

  auto addrow = [&](int s) {
    const ushort* r = X + (size_t)s * D + co;
    if constexpr (CPL == 2) {
      uint u = *(const uint*)r;
      acc[0] += u2f_lo(u); acc[1] += u2f_hi(u);
    } else {
      uint2 u = *(const uint2*)r;
      acc[0] += u2f_lo(u.x); acc[1] += u2f_hi(u.x);
      acc[2] += u2f_lo(u.y); acc[3] += u2f_hi(u.y);
    }
  };

  uint j = 0;
  for (; j + 4 <= dg; j += 4) {
    int s0 = csr[start + j],     s1 = csr[start + j + 1];
    int s2 = csr[start + j + 2], s3 = csr[start + j + 3];
    addrow(s0); addrow(s1); addrow(s2); addrow(s3);
  }
  for (; j < dg; ++j) addrow(csr[start + j]);

  float inv = 1.0f / (float)(dg < 1u ? 1u : dg);
  ushort* op = agg + (size_t)n * D + co;
  if constexpr (CPL == 2) {
    *(uint*)op = pack2(acc[0] * inv, acc[1] * inv);
  } else {
    uint2 o; o.x = pack2(acc[0] * inv, acc[1] * inv);
    o.y = pack2(acc[2] * inv, acc[3] * inv);
    *(uint2*)op = o;
  }
}

// ---------------------------------------------------------------------------
// MFMA GEMM v6: 64x256 block, 4 waves, wave = 64x64. A via LDS, W direct.
// K is COMPILE-TIME (128/256): K-loop unrolls, loads schedule across iters.
// Epilogue: block-wide 32x260 staging -> full 512B-row stores.
// RN: fused row-L2-normalize + GraphNorm moments. LN: fused graph-LN stats.
#define CS_P 260
template<int K, bool DUAL, bool RN, bool LN>
__global__ __launch_bounds__(256, 4) void gemm_mfma(
    const ushort* __restrict__ A1, int lda1, const ushort* __restrict__ W1,
    const ushort* __restrict__ A2, int lda2, const ushort* __restrict__ W2,
    const ushort* __restrict__ bias, const ushort* addend,   // addend may alias out
    ushort* out, int ldOut,
    float* __restrict__ m1, float* __restrict__ m2, float* __restrict__ st2)
{
  __shared__ __align__(16) unsigned char smem[34816];   // max(64*(K+8)*2, 32*260*4)
  ushort* As = (ushort*)smem;
  float*  Cs = (float*)smem;
  const int tid = threadIdx.x;
  const int lane = tid & 63, wave = tid >> 6;
  const int lr = lane & 15, quad = lane >> 4;
  const int m0 = blockIdx.x * 64;
  const int n0b = blockIdx.y * 256;
  const int n0 = n0b + wave * 64;
  constexpr int KP = K + 8;
  f32x4_t acc[4][4];
  #pragma unroll
  for (int rt = 0; rt < 4; ++rt)
    #pragma unroll
    for (int ct = 0; ct < 4; ++ct) acc[rt][ct] = (f32x4_t){0.f, 0.f, 0.f, 0.f};

  constexpr int lpr = K >> 3;
  constexpr int rpp = 256 / lpr;
  constexpr int passes = 64 / rpp;
  const int tr = tid / lpr, tc = (tid % lpr) * 8;

  // ---- stream 1 ----
  #pragma unroll
  for (int p = 0; p < passes; ++p) {
    int row = p * rpp + tr;
    *(bf16x8_t*)(As + row * KP + tc) =
        *(const bf16x8_t*)(A1 + (size_t)(m0 + row) * lda1 + tc);
  }
  __syncthreads();
  {
    const ushort* wp = W1 + (size_t)(n0 + lr) * K + quad * 8;
    for (int kb = 0; kb < K; kb += 32) {
      bf16x8_t a[4], b[4];
      #pragma unroll
      for (int ct = 0; ct < 4; ++ct) b[ct] = *(const bf16x8_t*)(wp + (size_t)(ct * 16) * K + kb);
      #pragma unroll
      for (int rt = 0; rt < 4; ++rt)
        a[rt] = *(const bf16x8_t*)(As + (rt * 16 + lr) * KP + kb + quad * 8);
      #pragma unroll
      for (int rt = 0; rt < 4; ++rt)
        #pragma unroll
        for (int ct = 0; ct < 4; ++ct)
          acc[rt][ct] = __builtin_amdgcn_mfma_f32_16x16x32_bf16(a[rt], b[ct], acc[rt][ct], 0, 0, 0);
    }
  }
  __syncthreads();
  // ---- stream 2 ----
  if constexpr (DUAL) {
    #pragma unroll
    for (int p = 0; p < passes; ++p) {
      int row = p * rpp + tr;
      *(bf16x8_t*)(As + row * KP + tc) =
          *(const bf16x8_t*)(A2 + (size_t)(m0 + row) * lda2 + tc);
    }
    __syncthreads();
    const ushort* wp = W2 + (size_t)(n0 + lr) * K + quad * 8;
    for (int kb = 0; kb < K; kb += 32) {
      bf16x8_t a[4], b[4];
      #pragma unroll
      for (int ct = 0; ct < 4; ++ct) b[ct] = *(const bf16x8_t*)(wp + (size_t)(ct * 16) * K + kb);
      #pragma unroll
      for (int rt = 0; rt < 4; ++rt)
        a[rt] = *(const bf16x8_t*)(As + (rt * 16 + lr) * KP + kb + quad * 8);
      #pragma unroll
      for (int rt = 0; rt < 4; ++rt)
        #pragma unroll
        for (int ct = 0; ct < 4; ++ct)
          acc[rt][ct] = __builtin_amdgcn_mfma_f32_16x16x32_bf16(a[rt], b[ct], acc[rt][ct], 0, 0, 0);
    }
    __syncthreads();
  }

  // ---- epilogue ----
  float bvs[4];
  if (RN && bias) {
    #pragma unroll
    for (int ct = 0; ct < 4; ++ct) bvs[ct] = bf2f(bias[n0 + ct * 16 + lr]);
  }
  float bvL[4] = {0.f, 0.f, 0.f, 0.f};
  if (!RN && bias) {
    #pragma unroll
    for (int j = 0; j < 4; ++j) bvL[j] = bf2f(bias[n0b + lane * 4 + j]);
  }
  float a1s[4] = {0.f, 0.f, 0.f, 0.f}, a2s[4] = {0.f, 0.f, 0.f, 0.f};
  float sln = 0.0f, qln = 0.0f;
  #pragma unroll
  for (int round = 0; round < 2; ++round) {
    #pragma unroll
    for (int rt2 = 0; rt2 < 2; ++rt2) {
      int rt = round * 2 + rt2;
      #pragma unroll
      for (int ct = 0; ct < 4; ++ct)
        #pragma unroll
        for (int r = 0; r < 4; ++r) {
          float v = acc[rt][ct][r];
          if constexpr (RN) v += bias ? bvs[ct] : 0.0f;
          Cs[(rt2 * 16 + quad * 4 + r) * CS_P + wave * 64 + ct * 16 + lr] = v;
        }
    }
    __syncthreads();
    #pragma unroll
    for (int it = 0; it < 8; ++it) {
      int row = wave * 8 + it;
      float4 v = *(const float4*)(Cs + row * CS_P + lane * 4);
      int grow = m0 + round * 32 + row;
      size_t ob = (size_t)grow * ldOut + n0b + lane * 4;
      if constexpr (RN) {
        float ss = v.x*v.x + v.y*v.y + v.z*v.z + v.w*v.w;
        ss = wredsum(ss);
        float inv = 1.0f / fmaxf(sqrtf(ss), 1e-12f);
        float r0 = v.x * inv, r1 = v.y * inv, r2 = v.z * inv, r3 = v.w * inv;
        a1s[0] += r0; a1s[1] += r1; a1s[2] += r2; a1s[3] += r3;
        a2s[0] += r0*r0; a2s[1] += r1*r1; a2s[2] += r2*r2; a2s[3] += r3*r3;
        uint2 o; o.x = pack2(r0, r1); o.y = pack2(r2, r3);
        *(uint2*)(out + ob) = o;
      } else {
        float r0 = v.x + bvL[0], r1 = v.y + bvL[1], r2 = v.z + bvL[2], r3 = v.w + bvL[3];
        if (addend) {
          uint2 ad = *(const uint2*)(addend + ob);
          r0 += u2f_lo(ad.x); r1 += u2f_hi(ad.x);
          r2 += u2f_lo(ad.y); r3 += u2f_hi(ad.y);
        }
        if constexpr (LN) {
          sln += r0 + r1 + r2 + r3;
          qln += r0*r0 + r1*r1 + r2*r2 + r3*r3;
        }
        uint2 o; o.x = pack2(r0, r1); o.y = pack2(r2, r3);
        *(uint2*)(out + ob) = o;
      }
    }
    __syncthreads();
  }
  if constexpr (RN) {
    const int g = m0 >> 9;
    #pragma unroll
    for (int k = 0; k < 4; ++k) {
      atomicAdd(&m1[g*C_ + lane * 4 + k], a1s[k]);
      atomicAdd(&m2[g*C_ + lane * 4 + k], a2s[k]);
    }
  }
  if constexpr (LN) {
    const int g = m0 >> 9;
    sln = wredsum(sln); qln = wredsum(qln);
    if (lane == 0) {
      atomicAdd(&st2[g * 2], sln);
      atomicAdd(&st2[g * 2 + 1], qln);
    }
  }
}

// ---------------------------------------------------------------------------
// GraphNorm + GELU + residual, param-cached. Block = 64 nodes of one graph;
// thread owns a fixed 8-channel slice. Params loaded ONCE, folded.
__global__ __launch_bounds__(256) void gn_gelu_add(const ushort* __restrict__ h,
    const ushort* res,
    const float* __restrict__ m1, const float* __restrict__ m2,
    const ushort* __restrict__ gw, const ushort* __restrict__ gb, const ushort* __restrict__ ga,
    ushort* out)
{
  const int tid = threadIdx.x;
  const int c = (tid * 8) & (C_ - 1);
  const int rowoff = tid >> 5;            // 0..7
  const int n0 = blockIdx.x * 64;
  const int g = n0 >> 9;
  float am[8], rs[8], bb[8];
  #pragma unroll
  for (int j = 0; j < 8; ++j) {
    int cc = c + j;
    float a  = bf2f(ga[cc]);
    float mm = m1[g*C_ + cc] * (1.0f / 512.0f);
    float q2 = m2[g*C_ + cc] * (1.0f / 512.0f);
    float var = q2 - a * (2.0f - a) * mm * mm;
    am[j] = a * mm;
    rs[j] = bf2f(gw[cc]) * rsqrtf(var + 1e-5f);
    bb[j] = bf2f(gb[cc]);
  }
  const size_t b0 = (size_t)(n0 + rowoff) * C_ + c;
  const ushort* hp = h + b0;
  const ushort* rp = res + b0;
  ushort* op = out + b0;
  #pragma unroll
  for (int p = 0; p < 8; ++p) {
    const size_t off = (size_t)p * 8 * C_;
    uint4 hv = *(const uint4*)(hp + off);
    uint4 rv = *(const uint4*)(rp + off);
    float hh[8] = {u2f_lo(hv.x), u2f_hi(hv.x), u2f_lo(hv.y), u2f_hi(hv.y),
                   u2f_lo(hv.z), u2f_hi(hv.z), u2f_lo(hv.w), u2f_hi(hv.w)};
    float rr[8] = {u2f_lo(rv.x), u2f_hi(rv.x), u2f_lo(rv.y), u2f_hi(rv.y),
                   u2f_lo(rv.z), u2f_hi(rv.z), u2f_lo(rv.w), u2f_hi(rv.w)};
    float oo[8];
    #pragma unroll
    for (int j = 0; j < 8; ++j) {
      float y = (hh[j] - am[j]) * rs[j] + bb[j];
      oo[j] = gelu_f(y) + rr[j];
    }
    uint4 ov;
    ov.x = pack2(oo[0], oo[1]); ov.y = pack2(oo[2], oo[3]);
    ov.z = pack2(oo[4], oo[5]); ov.w = pack2(oo[6], oo[7]);
    *(uint4*)(op + off) = ov;
  }
}

// ---------------------------------------------------------------------------
// MFMA attention: one block (512 thr) per (graph, head). Vt XOR-swizzled.
#define KS_P 72
#define VT_P 520
#define PW_P 40
__device__ __forceinline__ int vswz(int c){ return ((c >> 3) & 7) << 3; }
__global__ __launch_bounds__(512, 2) void attn_kernel(ushort* __restrict__ qkv)
{
  __shared__ __align__(16) ushort Ks[NP_ * KS_P];
  __shared__ __align__(16) ushort Vt[64 * VT_P];
  __shared__ ushort Pw[8][16 * PW_P];
  const int bid = blockIdx.x;
  const int g = bid >> 2, h = bid & 3;
  const int tid = threadIdx.x, lane = tid & 63, wave = tid >> 6;
  const int lr = lane & 15, quad = lane >> 4;
  const size_t base = (size_t)g * NP_ * C3_;
  const int qoff = h * 64, koff = C_ + h * 64, voff = 2 * C_ + h * 64;
  // staging: b128 global loads
  for (int idx = tid; idx < NP_ * 8; idx += 512) {
    int j = idx >> 3, c8 = (idx & 7) << 3;
    const ushort* row = qkv + base + (size_t)j * C3_;
    *(bf16x8_t*)(Ks + j * KS_P + c8) = *(const bf16x8_t*)(row + koff + c8);
    bf16x8_t vv = *(const bf16x8_t*)(row + voff + c8);
    #pragma unroll
    for (int m = 0; m < 8; ++m) {
      int c = c8 + m;
      Vt[c * VT_P + (j ^ vswz(c))] = (ushort)vv[m];
    }
  }
  __syncthreads();
  ushort* pw = &Pw[wave][0];
  const int q0 = wave * 64;
  for (int qt = 0; qt < 4; ++qt) {
    const int qr = q0 + qt * 16;
    const ushort* qp = qkv + base + (size_t)(qr + lr) * C3_ + qoff + quad * 8;
    bf16x8_t qa0 = *(const bf16x8_t*)(qp);
    bf16x8_t qa1 = *(const bf16x8_t*)(qp + 32);
    f32x4_t s[32];
    #pragma unroll
    for (int t = 0; t < 32; ++t) {
      const ushort* kp = Ks + (size_t)(t * 16 + lr) * KS_P + quad * 8;
      bf16x8_t b0 = *(const bf16x8_t*)(kp);
      bf16x8_t b1 = *(const bf16x8_t*)(kp + 32);
      f32x4_t a = (f32x4_t){0.f, 0.f, 0.f, 0.f};
      a = __builtin_amdgcn_mfma_f32_16x16x32_bf16(qa0, b0, a, 0, 0, 0);
      a = __builtin_amdgcn_mfma_f32_16x16x32_bf16(qa1, b1, a, 0, 0, 0);
      s[t] = a;
    }
    float invv[4];
    #pragma unroll
    for (int r = 0; r < 4; ++r) {
      float m = s[0][r];
      #pragma unroll
      for (int t = 1; t < 32; ++t) m = fmaxf(m, s[t][r]);
      #pragma unroll
      for (int off = 8; off; off >>= 1) m = fmaxf(m, __shfl_xor(m, off, 64));
      float sm = 0.0f;
      #pragma unroll
      for (int t = 0; t < 32; ++t) {
        float e = __expf((s[t][r] - m) * 0.125f);
        s[t][r] = e; sm += e;
      }
      #pragma unroll
      for (int off = 8; off; off >>= 1) sm += __shfl_xor(sm, off, 64);
      invv[r] = 1.0f / sm;
    }
    f32x4_t o[4];
    #pragma unroll
    for (int t = 0; t < 4; ++t) o[t] = (f32x4_t){0.f, 0.f, 0.f, 0.f};
    for (int kc = 0; kc < 16; ++kc) {
      #pragma unroll
      for (int half = 0; half < 2; ++half) {
        int t = kc * 2 + half;
        #pragma unroll
        for (int r = 0; r < 4; ++r)
          pw[(quad * 4 + r) * PW_P + half * 16 + lr] = f2bf(s[t][r] * invv[r]);
      }
      __threadfence_block();
      bf16x8_t pa = *(const bf16x8_t*)(pw + lr * PW_P + quad * 8);
      #pragma unroll
      for (int nt = 0; nt < 4; ++nt) {
        int vrow = nt * 16 + lr;
        const ushort* vp = Vt + (size_t)vrow * VT_P + ((kc * 32 + quad * 8) ^ vswz(vrow));
        bf16x8_t b = *(const bf16x8_t*)(vp);
        o[nt] = __builtin_amdgcn_mfma_f32_16x16x32_bf16(pa, b, o[nt], 0, 0, 0);
      }
    }
    #pragma unroll
    for (int nt = 0; nt < 4; ++nt)
      #pragma unroll
      for (int r = 0; r < 4; ++r)
        qkv[base + (size_t)(qr + quad * 4 + r) * C3_ + koff + nt * 16 + lr] =
            f2bf(o[nt][r]);
  }
}

// ---------------------------------------------------------------------------
// ln_gelu, param-cached: block = 64 nodes of one graph, thread = fixed 8 ch.
__global__ __launch_bounds__(256) void ln_gelu(const ushort* __restrict__ x2, const float* __restrict__ st2,
    const ushort* __restrict__ lw, const ushort* __restrict__ lb, ushort* __restrict__ x3)
{
  const int tid = threadIdx.x;
  const int c = (tid * 8) & (C_ - 1);
  const int rowoff = tid >> 5;
  const int n0 = blockIdx.x * 64;
  const int g = n0 >> 9;
  float S = st2[g * 2], Q = st2[g * 2 + 1];
  float mu = S * (1.0f / (NP_ * C_));
  float var = Q * (1.0f / (NP_ * C_)) - mu * mu;
  float rsg = rsqrtf(var + 1e-5f);
  float ww[8], bb[8];
  #pragma unroll
  for (int j = 0; j < 8; ++j) {
    int cc = c + j;
    ww[j] = rsg * bf2f(lw[cc]);
    bb[j] = bf2f(lb[cc]);
  }
  const size_t b0 = (size_t)(n0 + rowoff) * C_ + c;
  const ushort* xp = x2 + b0;
  ushort* op = x3 + b0;
  #pragma unroll
  for (int p = 0; p < 8; ++p) {
    const size_t off = (size_t)p * 8 * C_;
    uint4 v = *(const uint4*)(xp + off);
    float vv[8] = {u2f_lo(v.x), u2f_hi(v.x), u2f_lo(v.y), u2f_hi(v.y),
                   u2f_lo(v.z), u2f_hi(v.z), u2f_lo(v.w), u2f_hi(v.w)};
    float oo[8];
    #pragma unroll
    for (int j = 0; j < 8; ++j) {
      float y = (vv[j] - mu) * ww[j] + bb[j];
      oo[j] = gelu_f(y);
    }
    uint4 ov;
    ov.x = pack2(oo[0], oo[1]); ov.y = pack2(oo[2], oo[3]);
    ov.z = pack2(oo[4], oo[5]); ov.w = pack2(oo[6], oo[7]);
    *(uint4*)(op + off) = ov;
  }
}

// ---------------------------------------------------------------------------
// Pool: per-slice partials (grid 128x8) then fused combine+projection.
__global__ __launch_bounds__(256) void pool_part(const ushort* __restrict__ x3,
    float* __restrict__ psum, float* __restrict__ pmax)
{
  const int g = blockIdx.x, sl = blockIdx.y, c = threadIdx.x;
  const ushort* p = x3 + ((size_t)g * NP_ + sl * 64) * C_ + c;
  float s = 0.0f, mx = -3.0e38f;
  #pragma unroll 4
  for (int r = 0; r < 64; ++r) {
    float v = bf2f(p[(size_t)r * C_]);
    s += v; mx = fmaxf(mx, v);
  }
  psum[((size_t)g * 8 + sl) * C_ + c] = s;
  pmax[((size_t)g * 8 + sl) * C_ + c] = mx;
}

__global__ __launch_bounds__(256) void final_gemm(const float* __restrict__ psum,
    const float* __restrict__ pmax,
    const ushort* __restrict__ W, const ushort* __restrict__ b, void* __restrict__ out,
    const uint* __restrict__ flag)
{
  __shared__ float pl[C3_];
  const int g = blockIdx.x, c = threadIdx.x;
  float s = 0.0f, mx = -3.0e38f;
  #pragma unroll
  for (int sl = 0; sl < 8; ++sl) {
    s += psum[((size_t)g * 8 + sl) * C_ + c];
    mx = fmaxf(mx, pmax[((size_t)g * 8 + sl) * C_ + c]);
  }
  pl[c] = s * (1.0f / 512.0f);
  pl[C_ + c] = mx;
  pl[2 * C_ + c] = s;
  __syncthreads();
  float acc = bf2f(b[c]);
  const ushort* wr = W + (size_t)c * C3_;
  for (int k = 0; k < C3_; k += 2) {
    uint wv = *(const uint*)(wr + k);
    acc += pl[k] * u2f_lo(wv) + pl[k + 1] * u2f_hi(wv);
  }
  if (*flag) ((float*)out)[g * C_ + c] = acc;
  else       ((ushort*)out)[g * C_ + c] = f2bf(acc);
}

// ---------------------------------------------------------------------------
extern "C" void kernel_launch(void* const* d_in, const int* in_sizes, int n_in,
                              void* d_out, int out_size, void* d_ws, size_t ws_size,
                              hipStream_t stream)
{
  const int* ei   = (const int*)d_in[1];
  const int* srcp = ei;
  const int* dstp = ei + E_TOT;

  const size_t NC = (size_t)N_TOT * C_;                        // 16,777,216
  const size_t NEEDED = (4ull << 20) + 4 * NC * sizeof(ushort); // 132 MB
  if (ws_size < NEEDED) return;

  unsigned char* wsb = (unsigned char*)d_ws;
  uint*   deg    = (uint*)wsb;                          // 256 KB
  float*  mbuf   = (float*)(wsb + (256u << 10));        // 4 layers x (m1,m2) = 1 MB
  float*  st2    = (float*)(wsb + (1280u << 10));       // ln sums 1 KB (zeroed w/ mbuf)
  uint*   flag   = (uint*)(wsb + (1288u << 10));
  ushort* PB     = (ushort*)(wsb + (1792u << 10));      // param pool bf16 ~1.9MB
  ushort* S0     = (ushort*)(wsb + (4u << 20));         // x1
  ushort* S1     = S0 + NC;
  ushort* S2     = S1 + NC;
  ushort* S3     = S2 + NC;
  ushort* qkvb   = S1;                                  // [N][768] overlay
  ushort* XB     = S3;                                  // x bf16 (lower 16MB of S3)
  unsigned char* s3hi = (unsigned char*)(S3 + (size_t)N_TOT * DIN_);
  int*  csr    = (int*)s3hi;                            // 2 MB
  uint* rowptr = (uint*)(s3hi + (2u << 20));            // 256 KB
  uint* cursor = (uint*)(s3hi + (2u << 20) + (256u << 10));
  float* psum  = (float*)S2;                            // pool partials (S2 dead then)
  float* pmax  = psum + (size_t)B_GR * 8 * C_;

  // ---- dtype probe + import ----
  probe_dtype<<<1, 1, 0, stream>>>((const uint*)d_in[10], flag);
  CvtArgs ca;
  ca.s[0]  = { d_in[3],  O_L0LW };  ca.s[1]  = { d_in[4],  O_L0LB };
  ca.s[2]  = { d_in[5],  O_L0RW };  ca.s[3]  = { d_in[6],  O_L0RES };
  ca.s[4]  = { d_in[7],  O_LWL  };  ca.s[5]  = { d_in[8],  O_LBL  };
  ca.s[6]  = { d_in[9],  O_LWR  };  ca.s[7]  = { d_in[10], O_GNW  };
  ca.s[8]  = { d_in[11], O_GNB  };  ca.s[9]  = { d_in[12], O_GNA  };
  ca.s[10] = { d_in[13], O_AIW  };  ca.s[11] = { d_in[14], O_AIB  };
  ca.s[12] = { d_in[15], O_AOW  };  ca.s[13] = { d_in[16], O_AOB  };
  ca.s[14] = { d_in[17], O_LNW  };  ca.s[15] = { d_in[18], O_LNB  };
  ca.s[16] = { d_in[19], O_PLW  };  ca.s[17] = { d_in[20], O_PLB  };
  ca.s[18] = { nullptr,  TOTALP };
  cvt_params<<<(TOTALP + 255) / 256, 256, 0, stream>>>(ca, PB, flag);
  cvt_flat<<<(N_TOT * DIN_) / 1024, 256, 0, stream>>>(d_in[0], XB, flag);

  // ---- zero deg + moment buffers + ln sums (contiguous region) ----
  hipMemsetAsync(deg, 0, N_TOT * sizeof(uint), stream);
  hipMemsetAsync(mbuf, 0, (1u << 20) + 1024, stream);

  // ---- degree + CSR build ----
  deg_count<<<E_TOT / 256, 256, 0, stream>>>(dstp, deg);
  scan_deg<<<B_GR, 512, 0, stream>>>(deg, rowptr, cursor);
  scatter_edges<<<E_TOT / 256, 256, 0, stream>>>(srcp, dstp, cursor, csr);

  const size_t MSZ = (size_t)B_GR * C_;
  // ---- layer 0 (DIN=128 -> C=256) ----
  {
    float* m1 = mbuf;
    float* m2 = mbuf + MSZ * 4;
    sage_agg_csr<DIN_><<<N_TOT / 4, 256, 0, stream>>>(XB, csr, rowptr, deg, S1);
    gemm_mfma<DIN_, true, true, false><<<dim3(N_TOT / 64, 1), 256, 0, stream>>>(
        S1, DIN_, PB + O_L0LW, XB, DIN_, PB + O_L0RW, PB + O_L0LB, nullptr, S2, C_, m1, m2, nullptr);
    gemm_mfma<DIN_, false, false, false><<<dim3(N_TOT / 64, 1), 256, 0, stream>>>(
        XB, DIN_, PB + O_L0RES, nullptr, 0, nullptr, nullptr, nullptr, S0, C_, nullptr, nullptr, nullptr);
    gn_gelu_add<<<N_TOT / 64, 256, 0, stream>>>(S2, S0, m1, m2,
        PB + O_GNW, PB + O_GNB, PB + O_GNA, S0);
  }

  // ---- layers 1..3 (C -> C) ----
  for (int i = 0; i < 3; ++i) {
    float* m1 = mbuf + MSZ * (i + 1);
    float* m2 = mbuf + MSZ * 4 + MSZ * (i + 1);
    sage_agg_csr<C_><<<N_TOT / 4, 256, 0, stream>>>(S0, csr, rowptr, deg, S1);
    gemm_mfma<C_, true, true, false><<<dim3(N_TOT / 64, 1), 256, 0, stream>>>(
        S1, C_, PB + O_LWL + (size_t)i * C_ * C_, S0, C_, PB + O_LWR + (size_t)i * C_ * C_,
        PB + O_LBL + i * C_, nullptr, S2, C_, m1, m2, nullptr);
    gn_gelu_add<<<N_TOT / 64, 256, 0, stream>>>(S2, S0, m1, m2,
        PB + O_GNW + (i + 1) * C_, PB + O_GNB + (i + 1) * C_, PB + O_GNA + (i + 1) * C_, S0);
  }

  // ---- attention ----
  gemm_mfma<C_, false, false, false><<<dim3(N_TOT / 64, 3), 256, 0, stream>>>(
      S0, C_, PB + O_AIW, nullptr, 0, nullptr, PB + O_AIB, nullptr, qkvb, C3_, nullptr, nullptr, nullptr);
  attn_kernel<<<B_GR * H_, 512, 0, stream>>>(qkvb);
  // out-proj (+x1 residual) with fused graph-LN stats
  gemm_mfma<C_, false, false, true><<<dim3(N_TOT / 64, 1), 256, 0, stream>>>(
      qkvb + C_, C3_, PB + O_AOW, nullptr, 0, nullptr, PB + O_AOB, S0, S0, C_, nullptr, nullptr, st2);

  // ---- graph LayerNorm + gelu ----
  ln_gelu<<<N_TOT / 64, 256, 0, stream>>>(S0, st2, PB + O_LNW, PB + O_LNB, S1);

  // ---- pool + projection ----
  pool_part<<<dim3(B_GR, 8), 256, 0, stream>>>(S1, psum, pmax);
  final_gemm<<<B_GR, 256, 0, stream>>>(psum, pmax, PB + O_PLW, PB + O_PLB, d_out, flag);
}